// Round 1
// baseline (122.394 us; speedup 1.0000x reference)
//
#include <hip/hip_runtime.h>
#include <stdint.h>

// Multihead_Attention: Q/K/V proj (relu) -> per-head scores folded into one GEMM
// via Wo/8 column scaling -> softmax -> PV. Outputs: out [2048,1024] f32, attn.T [2048,2048] f32.
// All GEMMs: bf16 MFMA 16x16x32, 128x128 tile, BK=64, 4 waves, global_load_lds w=16,
// XOR chunk swizzle (linear LDS dest + inverse-swizzled global src + swizzled ds_read).

#define TQ 2048
#define TK 2048
#define HD 1024

#define DEVI __device__ __forceinline__

typedef __attribute__((ext_vector_type(8))) short bf16x8;
typedef __attribute__((ext_vector_type(4))) float f32x4;
typedef __attribute__((ext_vector_type(4))) unsigned short u16x4;

DEVI unsigned short f2bf(float f) {
  uint32_t u = __builtin_bit_cast(uint32_t, f);
  u += 0x7FFFu + ((u >> 16) & 1u);
  return (unsigned short)(u >> 16);
}
DEVI float bf2f(unsigned short h) {
  uint32_t u = ((uint32_t)h) << 16;
  return __builtin_bit_cast(float, u);
}

DEVI void gload_lds16(const void* g, void* l) {
  __builtin_amdgcn_global_load_lds((const __attribute__((address_space(1))) void*)g,
                                   (__attribute__((address_space(3))) void*)l,
                                   16, 0, 0);
}

// ---------------- GEMM mainloop: C[128x128] += A[128xK] * Bt[128xK]^T ------------
// A: bf16 row-major [M][lda] (K contiguous), Bt: bf16 row-major [N][ldb] (K contiguous).
// LDS tile 128x64 per operand, chunk = 8 bf16 = 16B. Chunk swizzle: lds chunk (r,c)
// holds global chunk (r, c ^ (r&7)); ds_read applies the same XOR.
DEVI void mfma_loop(const unsigned short* __restrict__ A,
                    const unsigned short* __restrict__ B,
                    int lda, int ldb, int K, int bm, int bn,
                    unsigned short* ldsA, unsigned short* ldsB,
                    f32x4 acc[4][4]) {
  const int tid = threadIdx.x;
  const int lane = tid & 63;
  const int wave = tid >> 6;
  const int wr = wave >> 1, wc = wave & 1;
  const int l15 = lane & 15, hi = lane >> 4;

#pragma unroll
  for (int i = 0; i < 4; i++)
#pragma unroll
    for (int j = 0; j < 4; j++) acc[i][j] = (f32x4)(0.0f);

  const unsigned short* Abase = A + (size_t)bm * 128 * lda;
  const unsigned short* Bbase = B + (size_t)bn * 128 * ldb;

  const int nkt = K >> 6;
  for (int kt = 0; kt < nkt; ++kt) {
    const int k0 = kt * 64;
    // stage 128x64 of A and B: 1024 chunks each, 4 per thread
#pragma unroll
    for (int i = 0; i < 4; i++) {
      int c = i * 256 + tid;      // linear chunk in LDS
      int r = c >> 3;             // tile row
      int cs = (c & 7) ^ (r & 7); // swizzled source chunk
      gload_lds16(Abase + (size_t)r * lda + k0 + cs * 8, ldsA + c * 8);
      gload_lds16(Bbase + (size_t)r * ldb + k0 + cs * 8, ldsB + c * 8);
    }
    __syncthreads();  // compiler emits vmcnt(0) drain here
#pragma unroll
    for (int kk = 0; kk < 2; kk++) {
      bf16x8 af[4], bf[4];
#pragma unroll
      for (int f = 0; f < 4; f++) {
        int ra = wr * 64 + f * 16 + l15;
        int ca = (kk * 4 + hi) ^ (ra & 7);
        af[f] = *(const bf16x8*)(ldsA + ra * 64 + ca * 8);
        int rb = wc * 64 + f * 16 + l15;
        int cb = (kk * 4 + hi) ^ (rb & 7);
        bf[f] = *(const bf16x8*)(ldsB + rb * 64 + cb * 8);
      }
#pragma unroll
      for (int fm = 0; fm < 4; fm++)
#pragma unroll
        for (int fn = 0; fn < 4; fn++)
          acc[fm][fn] = __builtin_amdgcn_mfma_f32_16x16x32_bf16(af[fm], bf[fn], acc[fm][fn], 0, 0, 0);
    }
    __syncthreads();
  }
}

// ------------- GEMM with plain f32 output (logits, PV) ----------------------------
__global__ __launch_bounds__(256)
void gemm_f32(const unsigned short* __restrict__ A, const unsigned short* __restrict__ B,
              float* __restrict__ C, int lda, int ldb, int ldc, int K) {
  __shared__ __align__(16) unsigned short ldsA[128 * 64];
  __shared__ __align__(16) unsigned short ldsB[128 * 64];
  const int bm = blockIdx.y, bn = blockIdx.x;
  f32x4 acc[4][4];
  mfma_loop(A, B, lda, ldb, K, bm, bn, ldsA, ldsB, acc);

  const int tid = threadIdx.x;
  const int lane = tid & 63;
  const int wave = tid >> 6;
  const int wr = wave >> 1, wc = wave & 1;
  const int l15 = lane & 15, hi = lane >> 4;
  const int row0 = bm * 128 + wr * 64;
  const int col0 = bn * 128 + wc * 64;
#pragma unroll
  for (int fm = 0; fm < 4; fm++)
#pragma unroll
    for (int fn = 0; fn < 4; fn++) {
      int cg = col0 + fn * 16 + l15;
      int rg = row0 + fm * 16 + hi * 4;
#pragma unroll
      for (int i = 0; i < 4; i++)
        C[(size_t)(rg + i) * ldc + cg] = acc[fm][fn][i];
    }
}

// ------------- batched projection GEMM: relu(X @ W^T + b) --------------------------
// z=0: Q -> Ql bf16 [TQ][HD]
// z=1: K -> Ks bf16 [TK][HD], scaled by Wo[col/64]*0.125 after relu
// z=2: V -> VT bf16 [HD][TK] (transposed store for the PV GEMM B operand)
__global__ __launch_bounds__(256)
void gemm_proj(const unsigned short* __restrict__ Qb, const unsigned short* __restrict__ Kb,
               const unsigned short* __restrict__ Vb,
               const unsigned short* __restrict__ Wqb, const unsigned short* __restrict__ Wkb,
               const unsigned short* __restrict__ Wvb,
               const float* __restrict__ bq, const float* __restrict__ bk,
               const float* __restrict__ bv, const float* __restrict__ Wo,
               unsigned short* __restrict__ Ql, unsigned short* __restrict__ Ks,
               unsigned short* __restrict__ VT) {
  __shared__ __align__(16) unsigned short ldsA[128 * 64];
  __shared__ __align__(16) unsigned short ldsB[128 * 64];
  const int z = blockIdx.z;
  const unsigned short* A = (z == 0) ? Qb : (z == 1) ? Kb : Vb;
  const unsigned short* B = (z == 0) ? Wqb : (z == 1) ? Wkb : Wvb;
  const float* bias = (z == 0) ? bq : (z == 1) ? bk : bv;

  const int bm = blockIdx.y, bn = blockIdx.x;
  f32x4 acc[4][4];
  mfma_loop(A, B, HD, HD, HD, bm, bn, ldsA, ldsB, acc);

  const int tid = threadIdx.x;
  const int lane = tid & 63;
  const int wave = tid >> 6;
  const int wr = wave >> 1, wc = wave & 1;
  const int l15 = lane & 15, hi = lane >> 4;
  const int row0 = bm * 128 + wr * 64;
  const int col0 = bn * 128 + wc * 64;

#pragma unroll
  for (int fm = 0; fm < 4; fm++)
#pragma unroll
    for (int fn = 0; fn < 4; fn++) {
      int cg = col0 + fn * 16 + l15;
      int rg = row0 + fm * 16 + hi * 4;
      float b = bias[cg];
      if (z == 2) {
        u16x4 o;
#pragma unroll
        for (int i = 0; i < 4; i++) o[i] = f2bf(fmaxf(acc[fm][fn][i] + b, 0.0f));
        *(u16x4*)(VT + (size_t)cg * TK + rg) = o;
      } else if (z == 1) {
        float s = 0.125f * Wo[cg >> 6];
#pragma unroll
        for (int i = 0; i < 4; i++)
          Ks[(size_t)(rg + i) * HD + cg] = f2bf(fmaxf(acc[fm][fn][i] + b, 0.0f) * s);
      } else {
#pragma unroll
        for (int i = 0; i < 4; i++)
          Ql[(size_t)(rg + i) * HD + cg] = f2bf(fmaxf(acc[fm][fn][i] + b, 0.0f));
      }
    }
}

// ------------- row softmax over 2048 logits -> bf16 attn ---------------------------
__global__ __launch_bounds__(256)
void softmax_k(const float* __restrict__ logits, unsigned short* __restrict__ attnb) {
  const int row = blockIdx.x;
  const int tid = threadIdx.x;
  const int lane = tid & 63;
  const int wave = tid >> 6;
  const float* lr = logits + (size_t)row * TK;

  f32x4 v0 = *(const f32x4*)(lr + tid * 8);
  f32x4 v1 = *(const f32x4*)(lr + tid * 8 + 4);
  float x[8];
#pragma unroll
  for (int j = 0; j < 4; j++) { x[j] = v0[j]; x[4 + j] = v1[j]; }

  float m = x[0];
#pragma unroll
  for (int j = 1; j < 8; j++) m = fmaxf(m, x[j]);
  for (int o = 32; o > 0; o >>= 1) m = fmaxf(m, __shfl_xor(m, o));
  __shared__ float redm[4], reds[4];
  if (lane == 0) redm[wave] = m;
  __syncthreads();
  m = fmaxf(fmaxf(redm[0], redm[1]), fmaxf(redm[2], redm[3]));

  const float L2E = 1.44269504088896341f;
  float e[8];
  float s = 0.0f;
#pragma unroll
  for (int j = 0; j < 8; j++) { e[j] = exp2f((x[j] - m) * L2E); s += e[j]; }
  for (int o = 32; o > 0; o >>= 1) s += __shfl_xor(s, o);
  if (lane == 0) reds[wave] = s;
  __syncthreads();
  s = reds[0] + reds[1] + reds[2] + reds[3];
  float inv = 1.0f / s;

  unsigned short* ar = attnb + (size_t)row * TK;
  u16x4 o0, o1;
#pragma unroll
  for (int j = 0; j < 4; j++) { o0[j] = f2bf(e[j] * inv); o1[j] = f2bf(e[4 + j] * inv); }
  *(u16x4*)(ar + tid * 8) = o0;
  *(u16x4*)(ar + tid * 8 + 4) = o1;
}

// ------------- transpose attn (bf16 [TQ][TK]) -> attn.T (f32 [TK][TQ]) -------------
__global__ __launch_bounds__(256)
void transpose_attn(const unsigned short* __restrict__ attnb, float* __restrict__ attnT) {
  __shared__ unsigned short tile[64][68];
  const int tr = blockIdx.y * 64;  // source row block
  const int tc = blockIdx.x * 64;  // source col block
  const int tid = threadIdx.x;
#pragma unroll
  for (int i = 0; i < 4; i++) {
    int q = i * 256 + tid;
    int r = q >> 4;
    int c4 = (q & 15) * 4;
    u16x4 v = *(const u16x4*)(attnb + (size_t)(tr + r) * TK + tc + c4);
    *(u16x4*)(&tile[r][c4]) = v;
  }
  __syncthreads();
#pragma unroll
  for (int i = 0; i < 4; i++) {
    int q = i * 256 + tid;
    int c = q >> 4;        // source col -> dest row
    int r4 = (q & 15) * 4; // source rows -> dest cols
    f32x4 o;
#pragma unroll
    for (int j = 0; j < 4; j++) o[j] = bf2f(tile[r4 + j][c]);
    *(f32x4*)(attnT + (size_t)(tc + c) * TQ + tr + r4) = o;
  }
}

// ------------- f32 -> bf16 convert -------------------------------------------------
__global__ __launch_bounds__(256)
void cvt_bf16(const float* __restrict__ s, unsigned short* __restrict__ d, int n4) {
  int i = blockIdx.x * 256 + threadIdx.x;
  if (i < n4) {
    f32x4 v = *(const f32x4*)(s + i * 4);
    u16x4 o;
#pragma unroll
    for (int j = 0; j < 4; j++) o[j] = f2bf(v[j]);
    *(u16x4*)(d + i * 4) = o;
  }
}

extern "C" void kernel_launch(void* const* d_in, const int* in_sizes, int n_in,
                              void* d_out, int out_size, void* d_ws, size_t ws_size,
                              hipStream_t stream) {
  const float* Q  = (const float*)d_in[0];
  const float* K  = (const float*)d_in[1];
  const float* V  = (const float*)d_in[2];
  const float* Wq = (const float*)d_in[3];
  const float* bq = (const float*)d_in[4];
  const float* Wk = (const float*)d_in[5];
  const float* bk = (const float*)d_in[6];
  const float* Wv = (const float*)d_in[7];
  const float* bv = (const float*)d_in[8];
  const float* Wo = (const float*)d_in[9];
  // bo (d_in[10]) unused: softmax is shift-invariant.

  uint8_t* w = (uint8_t*)d_ws;
  unsigned short* Qb  = (unsigned short*)(w + 0);                 // 4 MB
  unsigned short* Kb  = (unsigned short*)(w + 4194304);           // 4 MB
  unsigned short* Vb  = (unsigned short*)(w + 8388608);           // 4 MB
  unsigned short* Wqb = (unsigned short*)(w + 12582912);          // 2 MB
  unsigned short* Wkb = (unsigned short*)(w + 14680064);          // 2 MB
  unsigned short* Wvb = (unsigned short*)(w + 16777216);          // 2 MB
  unsigned short* Ql  = (unsigned short*)(w + 18874368);          // 4 MB
  unsigned short* Ks  = (unsigned short*)(w + 23068672);          // 4 MB
  unsigned short* VT  = (unsigned short*)(w + 27262976);          // 4 MB
  float*          logits = (float*)(w + 31457280);                // 16 MB
  unsigned short* attnb  = (unsigned short*)(w + 48234496);       // 8 MB
  // total 56,623,104 bytes

  float* outp  = (float*)d_out;                  // [2048][1024]
  float* attnT = outp + (size_t)TQ * HD;         // [2048][2048]

  // f32 -> bf16 converts
  cvt_bf16<<<dim3(2048), dim3(256), 0, stream>>>(Q, Qb, TQ * HD / 4);
  cvt_bf16<<<dim3(2048), dim3(256), 0, stream>>>(K, Kb, TK * HD / 4);
  cvt_bf16<<<dim3(2048), dim3(256), 0, stream>>>(V, Vb, TK * HD / 4);
  cvt_bf16<<<dim3(1024), dim3(256), 0, stream>>>(Wq, Wqb, HD * HD / 4);
  cvt_bf16<<<dim3(1024), dim3(256), 0, stream>>>(Wk, Wkb, HD * HD / 4);
  cvt_bf16<<<dim3(1024), dim3(256), 0, stream>>>(Wv, Wvb, HD * HD / 4);

  // projections (batched over z): M=2048, N=1024, K=1024
  gemm_proj<<<dim3(8, 16, 3), dim3(256), 0, stream>>>(Qb, Kb, Vb, Wqb, Wkb, Wvb,
                                                      bq, bk, bv, Wo, Ql, Ks, VT);

  // logits = Ql @ Ks^T : M=2048, N=2048, K=1024
  gemm_f32<<<dim3(16, 16), dim3(256), 0, stream>>>(Ql, Ks, logits, HD, HD, TK, HD);

  // softmax rows -> bf16 attn
  softmax_k<<<dim3(TQ), dim3(256), 0, stream>>>(logits, attnb);

  // out = attn @ V_l : M=2048, N=1024, K=2048 (B operand = VT, K-contiguous)
  gemm_f32<<<dim3(8, 16), dim3(256), 0, stream>>>(attnb, VT, outp, TK, TK, HD, TK);

  // attn.T output
  transpose_attn<<<dim3(32, 32), dim3(256), 0, stream>>>(attnb, attnT);
}

// Round 2
// 83.718 us; speedup vs baseline: 1.4620x; 1.4620x over previous
//
#include <hip/hip_runtime.h>
#include <stdint.h>

// Multihead_Attention on MI355X.
// Structure: cvt f32->bf16, batched relu-projections (Wo/8 folded into K columns),
// logits GEMM, row softmax, PV GEMM (split-K=2 + reduce), attn.T transpose.
// GEMMs: bf16 MFMA 16x16x32, 128x128 tile, BK=64, 8 waves (512 thr),
// double-buffered LDS 2-phase pipeline (T3-min), XOR chunk swizzle, XCD rect swizzle.

#define TQ 2048
#define TK 2048
#define HD 1024

#define DEVI __device__ __forceinline__

typedef __attribute__((ext_vector_type(8))) short bf16x8;
typedef __attribute__((ext_vector_type(4))) float f32x4;
typedef __attribute__((ext_vector_type(4))) unsigned short u16x4;
typedef unsigned short ushort_t;

DEVI unsigned short f2bf(float f) {
  uint32_t u = __builtin_bit_cast(uint32_t, f);
  u += 0x7FFFu + ((u >> 16) & 1u);
  return (unsigned short)(u >> 16);
}
DEVI float bf2f(unsigned short h) {
  uint32_t u = ((uint32_t)h) << 16;
  return __builtin_bit_cast(float, u);
}

DEVI void gload_lds16(const void* g, void* l) {
  __builtin_amdgcn_global_load_lds((const __attribute__((address_space(1))) void*)g,
                                   (__attribute__((address_space(3))) void*)l,
                                   16, 0, 0);
}

// ---- stage one 128x64 bf16 tile pair into LDS (512 threads, 2 chunks each/operand)
// chunk = 8 bf16 = 16B. LDS linear dest; source chunk col XOR-swizzled by row (rule 21).
DEVI void stage_tiles(const unsigned short* __restrict__ Ab, const unsigned short* __restrict__ Bb,
                      int lda, int ldb, int k0,
                      unsigned short* lA, unsigned short* lB, int tid) {
#pragma unroll
  for (int i = 0; i < 2; i++) {
    int c = i * 512 + tid;       // linear chunk id in LDS [0,1024)
    int r = c >> 3;              // tile row [0,128)
    int cs = (c & 7) ^ (r & 7);  // swizzled source chunk col
    gload_lds16(Ab + (size_t)r * lda + k0 + cs * 8, lA + c * 8);
    gload_lds16(Bb + (size_t)r * ldb + k0 + cs * 8, lB + c * 8);
  }
}

// ---- compute one staged 64-K-step: per wave 64x32 output (acc[4][2])
DEVI void compute_kt(const unsigned short* lA, const unsigned short* lB,
                     f32x4 acc[4][2], int wr, int wc, int l15, int hi) {
#pragma unroll
  for (int kk = 0; kk < 2; kk++) {
    bf16x8 af[4], bfr[2];
#pragma unroll
    for (int f = 0; f < 4; f++) {
      int ra = wr * 64 + f * 16 + l15;
      int ca = (kk * 4 + hi) ^ (ra & 7);
      af[f] = *(const bf16x8*)(lA + ra * 64 + ca * 8);
    }
#pragma unroll
    for (int f = 0; f < 2; f++) {
      int rb = wc * 32 + f * 16 + l15;
      int cb = (kk * 4 + hi) ^ (rb & 7);
      bfr[f] = *(const bf16x8*)(lB + rb * 64 + cb * 8);
    }
#pragma unroll
    for (int fm = 0; fm < 4; fm++)
#pragma unroll
      for (int fn = 0; fn < 2; fn++)
        acc[fm][fn] = __builtin_amdgcn_mfma_f32_16x16x32_bf16(af[fm], bfr[fn], acc[fm][fn], 0, 0, 0);
  }
}

// ---- double-buffered main loop (2-phase T3-min). nkt assumed even, >=2.
DEVI void mfma_loop_db(const unsigned short* __restrict__ A, const unsigned short* __restrict__ B,
                       int lda, int ldb, int K, unsigned short* lds, f32x4 acc[4][2]) {
  const int tid = threadIdx.x;
  const int lane = tid & 63;
  const int wave = tid >> 6;
  const int wr = wave >> 2, wc = wave & 3;   // 2 x 4 wave grid
  const int l15 = lane & 15, hi = lane >> 4;

#pragma unroll
  for (int i = 0; i < 4; i++)
#pragma unroll
    for (int j = 0; j < 2; j++) acc[i][j] = (f32x4)(0.0f);

  unsigned short* lA0 = lds;
  unsigned short* lB0 = lds + 8192;
  unsigned short* lA1 = lds + 16384;
  unsigned short* lB1 = lds + 24576;

  const int nkt = K >> 6;
  stage_tiles(A, B, lda, ldb, 0, lA0, lB0, tid);
  __syncthreads();
  for (int kt = 0; kt < nkt; kt += 2) {
    if (kt + 1 < nkt) stage_tiles(A, B, lda, ldb, (kt + 1) * 64, lA1, lB1, tid);
    compute_kt(lA0, lB0, acc, wr, wc, l15, hi);
    __syncthreads();   // drains b1 loads (hidden under compute of b0)
    if (kt + 1 < nkt) {
      if (kt + 2 < nkt) stage_tiles(A, B, lda, ldb, (kt + 2) * 64, lA0, lB0, tid);
      compute_kt(lA1, lB1, acc, wr, wc, l15, hi);
      __syncthreads();
    }
  }
}

// ---- XCD rectangle decode: grid of MT x NT tiles, nb blocks in blockIdx.x.
// XCD x gets a contiguous sub-rectangle so per-XCD footprint fits 4MB L2.
DEVI void xcd_decode_16x16(int d, int& bm, int& bn) {  // 256 blocks, 16x16 tiles
  int x = d & 7, j = d >> 3;                           // XCD, index within
  bm = ((x >> 1) << 2) + (j >> 3);                     // 4 bm-rows per XCD
  bn = ((x & 1) << 3) + (j & 7);                       // 8 bn-cols per XCD
}
DEVI void xcd_decode_16x8(int d, int& bm, int& bn) {   // 128 blocks, 16x8 tiles
  int x = d & 7, j = d >> 3;
  bm = ((x >> 1) << 2) + (j >> 2);                     // 4 bm-rows
  bn = ((x & 1) << 2) + (j & 3);                       // 4 bn-cols
}

// ------------- logits = Ql @ Ks^T : [2048,2048] f32 -------------------------------
__global__ __launch_bounds__(512)
void gemm_logits(const unsigned short* __restrict__ Ql, const unsigned short* __restrict__ Ks,
                 float* __restrict__ C) {
  __shared__ __align__(16) unsigned short lds[32768];  // 64 KB
  int bm, bn;
  xcd_decode_16x16(blockIdx.x, bm, bn);
  f32x4 acc[4][2];
  mfma_loop_db(Ql + (size_t)bm * 128 * HD, Ks + (size_t)bn * 128 * HD, HD, HD, HD, lds, acc);

  const int tid = threadIdx.x;
  const int lane = tid & 63, wave = tid >> 6;
  const int wr = wave >> 2, wc = wave & 3;
  const int l15 = lane & 15, hi = lane >> 4;
  const int row0 = bm * 128 + wr * 64;
  const int col0 = bn * 128 + wc * 32;
#pragma unroll
  for (int fm = 0; fm < 4; fm++)
#pragma unroll
    for (int fn = 0; fn < 2; fn++) {
      int cg = col0 + fn * 16 + l15;
      int rg = row0 + fm * 16 + hi * 4;
#pragma unroll
      for (int i = 0; i < 4; i++)
        C[(size_t)(rg + i) * TK + cg] = acc[fm][fn][i];
    }
}

// ------------- PV partial: out_part[ks] = attn[:, ks*1024:+1024] @ VT^T ------------
__global__ __launch_bounds__(512)
void gemm_pv(const unsigned short* __restrict__ attnb, const unsigned short* __restrict__ VT,
             float* __restrict__ part) {
  __shared__ __align__(16) unsigned short lds[32768];
  int bm, bn;
  xcd_decode_16x8(blockIdx.x, bm, bn);
  const int ks = blockIdx.y;
  f32x4 acc[4][2];
  mfma_loop_db(attnb + (size_t)bm * 128 * TK + ks * 1024,
               VT + (size_t)bn * 128 * TK + ks * 1024, TK, TK, 1024, lds, acc);

  float* Cp = part + (size_t)ks * TQ * HD;
  const int tid = threadIdx.x;
  const int lane = tid & 63, wave = tid >> 6;
  const int wr = wave >> 2, wc = wave & 3;
  const int l15 = lane & 15, hi = lane >> 4;
  const int row0 = bm * 128 + wr * 64;
  const int col0 = bn * 128 + wc * 32;
#pragma unroll
  for (int fm = 0; fm < 4; fm++)
#pragma unroll
    for (int fn = 0; fn < 2; fn++) {
      int cg = col0 + fn * 16 + l15;
      int rg = row0 + fm * 16 + hi * 4;
#pragma unroll
      for (int i = 0; i < 4; i++)
        Cp[(size_t)(rg + i) * HD + cg] = acc[fm][fn][i];
    }
}

// ------------- batched projection: relu(X @ W^T + b), z selects Q/K/V --------------
__global__ __launch_bounds__(512)
void gemm_proj(const unsigned short* __restrict__ Qb, const unsigned short* __restrict__ Kb,
               const unsigned short* __restrict__ Vb,
               const unsigned short* __restrict__ Wqb, const unsigned short* __restrict__ Wkb,
               const unsigned short* __restrict__ Wvb,
               const float* __restrict__ bq, const float* __restrict__ bk,
               const float* __restrict__ bv, const float* __restrict__ Wo,
               unsigned short* __restrict__ Ql, unsigned short* __restrict__ Ks,
               unsigned short* __restrict__ VT) {
  __shared__ __align__(16) unsigned short lds[32768];
  const int z = blockIdx.y;
  const unsigned short* A = (z == 0) ? Qb : (z == 1) ? Kb : Vb;
  const unsigned short* B = (z == 0) ? Wqb : (z == 1) ? Wkb : Wvb;
  const float* bias = (z == 0) ? bq : (z == 1) ? bk : bv;

  int bm, bn;
  xcd_decode_16x8(blockIdx.x, bm, bn);
  f32x4 acc[4][2];
  mfma_loop_db(A + (size_t)bm * 128 * HD, B + (size_t)bn * 128 * HD, HD, HD, HD, lds, acc);

  const int tid = threadIdx.x;
  const int lane = tid & 63, wave = tid >> 6;
  const int wr = wave >> 2, wc = wave & 3;
  const int l15 = lane & 15, hi = lane >> 4;
  const int row0 = bm * 128 + wr * 64;
  const int col0 = bn * 128 + wc * 32;

#pragma unroll
  for (int fm = 0; fm < 4; fm++)
#pragma unroll
    for (int fn = 0; fn < 2; fn++) {
      int cg = col0 + fn * 16 + l15;
      int rg = row0 + fm * 16 + hi * 4;
      float b = bias[cg];
      if (z == 2) {
        u16x4 o;
#pragma unroll
        for (int i = 0; i < 4; i++) o[i] = f2bf(fmaxf(acc[fm][fn][i] + b, 0.0f));
        *(u16x4*)(VT + (size_t)cg * TK + rg) = o;   // transposed store for PV B-operand
      } else if (z == 1) {
        float s = 0.125f * Wo[cg >> 6];             // fold Wo/sqrt(64) into K columns
#pragma unroll
        for (int i = 0; i < 4; i++)
          Ks[(size_t)(rg + i) * HD + cg] = f2bf(fmaxf(acc[fm][fn][i] + b, 0.0f) * s);
      } else {
#pragma unroll
        for (int i = 0; i < 4; i++)
          Ql[(size_t)(rg + i) * HD + cg] = f2bf(fmaxf(acc[fm][fn][i] + b, 0.0f));
      }
    }
}

// ------------- row softmax over 2048 logits -> bf16 attn ---------------------------
__global__ __launch_bounds__(256)
void softmax_k(const float* __restrict__ logits, unsigned short* __restrict__ attnb) {
  const int row = blockIdx.x;
  const int tid = threadIdx.x;
  const int lane = tid & 63;
  const int wave = tid >> 6;
  const float* lr = logits + (size_t)row * TK;

  f32x4 v0 = *(const f32x4*)(lr + tid * 8);
  f32x4 v1 = *(const f32x4*)(lr + tid * 8 + 4);
  float x[8];
#pragma unroll
  for (int j = 0; j < 4; j++) { x[j] = v0[j]; x[4 + j] = v1[j]; }

  float m = x[0];
#pragma unroll
  for (int j = 1; j < 8; j++) m = fmaxf(m, x[j]);
  for (int o = 32; o > 0; o >>= 1) m = fmaxf(m, __shfl_xor(m, o));
  __shared__ float redm[4], reds[4];
  if (lane == 0) redm[wave] = m;
  __syncthreads();
  m = fmaxf(fmaxf(redm[0], redm[1]), fmaxf(redm[2], redm[3]));

  const float L2E = 1.44269504088896341f;
  float e[8];
  float s = 0.0f;
#pragma unroll
  for (int j = 0; j < 8; j++) { e[j] = exp2f((x[j] - m) * L2E); s += e[j]; }
  for (int o = 32; o > 0; o >>= 1) s += __shfl_xor(s, o);
  if (lane == 0) reds[wave] = s;
  __syncthreads();
  s = reds[0] + reds[1] + reds[2] + reds[3];
  float inv = 1.0f / s;

  unsigned short* ar = attnb + (size_t)row * TK;
  u16x4 o0, o1;
#pragma unroll
  for (int j = 0; j < 4; j++) { o0[j] = f2bf(e[j] * inv); o1[j] = f2bf(e[4 + j] * inv); }
  *(u16x4*)(ar + tid * 8) = o0;
  *(u16x4*)(ar + tid * 8 + 4) = o1;
}

// ------------- transpose attn (bf16 [TQ][TK]) -> attn.T (f32 [TK][TQ]) -------------
__global__ __launch_bounds__(256)
void transpose_attn(const unsigned short* __restrict__ attnb, float* __restrict__ attnT) {
  __shared__ unsigned short tile[64][68];
  const int tr = blockIdx.y * 64;
  const int tc = blockIdx.x * 64;
  const int tid = threadIdx.x;
#pragma unroll
  for (int i = 0; i < 4; i++) {
    int q = i * 256 + tid;
    int r = q >> 4;
    int c4 = (q & 15) * 4;
    u16x4 v = *(const u16x4*)(attnb + (size_t)(tr + r) * TK + tc + c4);
    *(u16x4*)(&tile[r][c4]) = v;
  }
  __syncthreads();
#pragma unroll
  for (int i = 0; i < 4; i++) {
    int q = i * 256 + tid;
    int c = q >> 4;
    int r4 = (q & 15) * 4;
    f32x4 o;
#pragma unroll
    for (int j = 0; j < 4; j++) o[j] = bf2f(tile[r4 + j][c]);
    *(f32x4*)(attnT + (size_t)(tc + c) * TQ + tr + r4) = o;
  }
}

// ------------- fused f32 -> bf16 converts (3 tensors per launch) -------------------
__global__ __launch_bounds__(256)
void cvt3(const float* __restrict__ a, const float* __restrict__ b, const float* __restrict__ c,
          unsigned short* __restrict__ da, unsigned short* __restrict__ db,
          unsigned short* __restrict__ dc, int n4) {
  const int z = blockIdx.y;
  const float* s = (z == 0) ? a : (z == 1) ? b : c;
  unsigned short* d = (z == 0) ? da : (z == 1) ? db : dc;
  int i = blockIdx.x * 256 + threadIdx.x;
  if (i < n4) {
    f32x4 v = *(const f32x4*)(s + i * 4);
    u16x4 o;
#pragma unroll
    for (int j = 0; j < 4; j++) o[j] = f2bf(v[j]);
    *(u16x4*)(d + i * 4) = o;
  }
}

// ------------- PV split-K reduce ---------------------------------------------------
__global__ __launch_bounds__(256)
void reduce_add(const float* __restrict__ p0, const float* __restrict__ p1,
                float* __restrict__ out, int n4) {
  int i = blockIdx.x * 256 + threadIdx.x;
  if (i < n4) {
    f32x4 a = *(const f32x4*)(p0 + i * 4);
    f32x4 b = *(const f32x4*)(p1 + i * 4);
    f32x4 o;
#pragma unroll
    for (int j = 0; j < 4; j++) o[j] = a[j] + b[j];
    *(f32x4*)(out + i * 4) = o;
  }
}

extern "C" void kernel_launch(void* const* d_in, const int* in_sizes, int n_in,
                              void* d_out, int out_size, void* d_ws, size_t ws_size,
                              hipStream_t stream) {
  const float* Q  = (const float*)d_in[0];
  const float* K  = (const float*)d_in[1];
  const float* V  = (const float*)d_in[2];
  const float* Wq = (const float*)d_in[3];
  const float* bq = (const float*)d_in[4];
  const float* Wk = (const float*)d_in[5];
  const float* bk = (const float*)d_in[6];
  const float* Wv = (const float*)d_in[7];
  const float* bv = (const float*)d_in[8];
  const float* Wo = (const float*)d_in[9];
  // bo unused: softmax shift-invariant.

  uint8_t* w = (uint8_t*)d_ws;
  unsigned short* Qb  = (unsigned short*)(w + 0);            // 4 MB
  unsigned short* Kb  = (unsigned short*)(w + 4194304);      // 4 MB
  unsigned short* Vb  = (unsigned short*)(w + 8388608);      // 4 MB
  unsigned short* Wqb = (unsigned short*)(w + 12582912);     // 2 MB
  unsigned short* Wkb = (unsigned short*)(w + 14680064);     // 2 MB
  unsigned short* Wvb = (unsigned short*)(w + 16777216);     // 2 MB
  unsigned short* Ql  = (unsigned short*)(w + 18874368);     // 4 MB
  unsigned short* Ks  = (unsigned short*)(w + 23068672);     // 4 MB
  unsigned short* VT  = (unsigned short*)(w + 27262976);     // 4 MB
  float*          logits = (float*)(w + 31457280);           // 16 MB
  unsigned short* attnb  = (unsigned short*)(w + 48234496);  // 8 MB
  // PV partials overlay Qb..Wkb (dead after proj): 2 x 8 MB
  float* p0 = (float*)(w + 0);
  float* p1 = (float*)(w + 8388608);

  float* outp  = (float*)d_out;              // [2048][1024]
  float* attnT = outp + (size_t)TQ * HD;     // [2048][2048]

  cvt3<<<dim3(2048, 3), dim3(256), 0, stream>>>(Q, K, V, Qb, Kb, Vb, TQ * HD / 4);
  cvt3<<<dim3(1024, 3), dim3(256), 0, stream>>>(Wq, Wk, Wv, Wqb, Wkb, Wvb, HD * HD / 4);

  // projections: M=2048, N=1024, K=1024, z in {Q,K,V}
  gemm_proj<<<dim3(128, 3), dim3(512), 0, stream>>>(Qb, Kb, Vb, Wqb, Wkb, Wvb,
                                                    bq, bk, bv, Wo, Ql, Ks, VT);

  // logits: M=2048, N=2048, K=1024
  gemm_logits<<<dim3(256), dim3(512), 0, stream>>>(Ql, Ks, logits);

  softmax_k<<<dim3(TQ), dim3(256), 0, stream>>>(logits, attnb);

  // PV: M=2048, N=1024, K=2048 split into 2x1024 (partials overlay dead proj bufs)
  gemm_pv<<<dim3(128, 2), dim3(512), 0, stream>>>(attnb, VT, p0);
  reduce_add<<<dim3(2048), dim3(256), 0, stream>>>(p0, p1, outp, TQ * HD / 4);

  transpose_attn<<<dim3(32, 32), dim3(256), 0, stream>>>(attnb, attnT);
}

// Round 3
// 83.083 us; speedup vs baseline: 1.4731x; 1.0076x over previous
//
#include <hip/hip_runtime.h>
#include <stdint.h>

// Multihead_Attention on MI355X (gfx950).
// cvt6 -> proj(relu, Wo/8 folded into K cols, V stored transposed) -> logits GEMM
// -> softmax -> [PV GEMM + attn.T transpose in one launch].
// GEMM core: bf16 MFMA 16x16x32, BM=128, BK=64, 512 thr, 4-buffer LDS pipeline,
// counted s_waitcnt vmcnt(N) (T3+T4), setprio around MFMA (T5), XOR chunk swizzle,
// XCD rectangle swizzle (per-XCD operand panels <= 4MB L2).

#define TQ 2048
#define TK 2048
#define HD 1024

#define DEVI __device__ __forceinline__

typedef __attribute__((ext_vector_type(8))) short bf16x8;
typedef __attribute__((ext_vector_type(4))) float f32x4;
typedef __attribute__((ext_vector_type(4))) unsigned short u16x4;
typedef unsigned short ushort_t;

DEVI unsigned short f2bf(float f) {
  uint32_t u = __builtin_bit_cast(uint32_t, f);
  u += 0x7FFFu + ((u >> 16) & 1u);
  return (unsigned short)(u >> 16);
}
DEVI float bf2f(unsigned short h) {
  uint32_t u = ((uint32_t)h) << 16;
  return __builtin_bit_cast(float, u);
}
DEVI void gload_lds16(const void* g, void* l) {
  __builtin_amdgcn_global_load_lds((const __attribute__((address_space(1))) void*)g,
                                   (__attribute__((address_space(3))) void*)l,
                                   16, 0, 0);
}
template<int N> DEVI void wait_vm() { asm volatile("s_waitcnt vmcnt(%0)" :: "n"(N) : "memory"); }
DEVI void wait_lgkm0() { asm volatile("s_waitcnt lgkmcnt(0)" ::: "memory"); }
#define SBAR() __builtin_amdgcn_s_barrier()

// ---- stage one K-step tile pair (A 128x64, B BNx64 bf16) into one LDS buffer.
// 512 threads. Linear LDS dest (gload_lds requirement), source col XOR-swizzled.
template<int BN>
DEVI void stageT(const unsigned short* __restrict__ A, const unsigned short* __restrict__ B,
                 int lda, int ldb, int k0, unsigned short* buf, int tid) {
#pragma unroll
  for (int i = 0; i < 2; i++) {              // A: 128 rows x 8 chunks = 1024 chunks
    int c = i * 512 + tid;
    int r = c >> 3;
    int cs = (c & 7) ^ (r & 7);
    gload_lds16(A + (size_t)r * lda + k0 + cs * 8, buf + c * 8);
  }
#pragma unroll
  for (int i = 0; i < BN / 64; i++) {        // B: BN rows x 8 chunks
    int c = i * 512 + tid;
    int r = c >> 3;
    int cs = (c & 7) ^ (r & 7);
    gload_lds16(B + (size_t)r * ldb + k0 + cs * 8, buf + 8192 + c * 8);
  }
}

// ---- one staged 64-K-step of MFMA. BN=128: wave 64x32 (acc[4][2]); BN=64: 32x32 (acc[2][2]).
template<int BN>
DEVI void computeT(const unsigned short* lA, const unsigned short* lB, f32x4 acc[4][2],
                   int wr, int wc, int l15, int hi) {
  constexpr int FM = (BN == 128) ? 4 : 2;
  constexpr int WMR = (BN == 128) ? 64 : 32;
#pragma unroll
  for (int kk = 0; kk < 2; kk++) {
    bf16x8 af[4], bfr[2];
#pragma unroll
    for (int f = 0; f < FM; f++) {
      int ra = wr * WMR + f * 16 + l15;
      int ca = (kk * 4 + hi) ^ (ra & 7);
      af[f] = *(const bf16x8*)(lA + ra * 64 + ca * 8);
    }
#pragma unroll
    for (int f = 0; f < 2; f++) {
      int rb = wc * 32 + f * 16 + l15;
      int cb = (kk * 4 + hi) ^ (rb & 7);
      bfr[f] = *(const bf16x8*)(lB + rb * 64 + cb * 8);
    }
#pragma unroll
    for (int fm = 0; fm < FM; fm++)
#pragma unroll
      for (int fn = 0; fn < 2; fn++)
        acc[fm][fn] = __builtin_amdgcn_mfma_f32_16x16x32_bf16(af[fm], bfr[fn], acc[fm][fn], 0, 0, 0);
  }
}

// ---- deep pipeline: 4 LDS buffers, 3 stages in flight, counted vmcnt.
// Ledger: stage(t+4)->buf[t&3] issues only after barrier #2 of iter t, i.e. after
// ALL waves finished compute(t) (lgkmcnt(0) drained). Reads of buf[t&3] at iter t+4
// are guarded by wait_vm leaving <=3 stages outstanding => stage t+4 landed.
template<int BN, int NKT>
DEVI void mfma_pipeline(const unsigned short* __restrict__ A, const unsigned short* __restrict__ B,
                        int lda, int ldb, unsigned short* lds, f32x4 acc[4][2]) {
  constexpr int FM = (BN == 128) ? 4 : 2;
  constexpr int LPS = 2 + BN / 64;           // loads per stage per thread (4 or 3)
  constexpr int BSTR = 8192 + BN * 64;       // buffer stride in shorts
  const int tid = threadIdx.x;
  const int lane = tid & 63, wave = tid >> 6;
  const int l15 = lane & 15, hi = lane >> 4;
  const int wr = (BN == 128) ? (wave >> 2) : (wave >> 1);
  const int wc = (BN == 128) ? (wave & 3) : (wave & 1);

#pragma unroll
  for (int i = 0; i < FM; i++)
#pragma unroll
    for (int j = 0; j < 2; j++) acc[i][j] = (f32x4)(0.0f);

#pragma unroll
  for (int s = 0; s < 4; s++) stageT<BN>(A, B, lda, ldb, s * 64, lds + s * BSTR, tid);

#pragma unroll 1
  for (int t = 0; t < NKT; ++t) {
    if (t < NKT - 3) wait_vm<3 * LPS>();
    else if (t == NKT - 3) wait_vm<2 * LPS>();
    else if (t == NKT - 2) wait_vm<LPS>();
    else wait_vm<0>();
    SBAR();                                   // buf t ready on every wave
    unsigned short* buf = lds + (t & 3) * BSTR;
    __builtin_amdgcn_s_setprio(1);
    computeT<BN>(buf, buf + 8192, acc, wr, wc, l15, hi);
    __builtin_amdgcn_s_setprio(0);
    wait_lgkm0();                             // all my ds_reads consumed
    SBAR();                                   // all waves done reading buf
    if (t + 4 < NKT) stageT<BN>(A, B, lda, ldb, (t + 4) * 64, buf, tid);
  }
}

// ------------- batched projection: relu(X @ W^T + b), BN=64, 768 blocks ------------
__global__ __launch_bounds__(512)
void gemm_proj(const unsigned short* __restrict__ Qb, const unsigned short* __restrict__ Kb,
               const unsigned short* __restrict__ Vb,
               const unsigned short* __restrict__ Wqb, const unsigned short* __restrict__ Wkb,
               const unsigned short* __restrict__ Wvb,
               const float* __restrict__ bq, const float* __restrict__ bk,
               const float* __restrict__ bv, const float* __restrict__ Wo,
               unsigned short* __restrict__ Ql, unsigned short* __restrict__ Ks,
               unsigned short* __restrict__ VT) {
  __shared__ __align__(16) unsigned short lds[4 * 12288];  // 96 KB
  const int bid = blockIdx.x;
  const int x = bid & 7, j = bid >> 3;     // XCD, index within (96 per XCD)
  const int z = j >> 5;                    // 32 tiles per z per XCD
  const int jj = j & 31;
  const int bm = (x & 3) * 4 + (jj >> 3);  // [0,16)
  const int bn = (x >> 2) * 8 + (jj & 7);  // [0,16)

  const unsigned short* A = (z == 0) ? Qb : (z == 1) ? Kb : Vb;
  const unsigned short* B = (z == 0) ? Wqb : (z == 1) ? Wkb : Wvb;
  const float* bias = (z == 0) ? bq : (z == 1) ? bk : bv;

  f32x4 acc[4][2];
  mfma_pipeline<64, 16>(A + (size_t)bm * 128 * HD, B + (size_t)bn * 64 * HD, HD, HD, lds, acc);

  const int tid = threadIdx.x;
  const int lane = tid & 63, wave = tid >> 6;
  const int wr = wave >> 1, wc = wave & 1;
  const int l15 = lane & 15, hi = lane >> 4;
  const int row0 = bm * 128 + wr * 32;
  const int col0 = bn * 64 + wc * 32;

#pragma unroll
  for (int fm = 0; fm < 2; fm++)
#pragma unroll
    for (int fn = 0; fn < 2; fn++) {
      int cg = col0 + fn * 16 + l15;
      int rg = row0 + fm * 16 + hi * 4;
      float b = bias[cg];
      if (z == 2) {
        u16x4 o;
#pragma unroll
        for (int i = 0; i < 4; i++) o[i] = f2bf(fmaxf(acc[fm][fn][i] + b, 0.0f));
        *(u16x4*)(VT + (size_t)cg * TK + rg) = o;   // transposed store for PV B operand
      } else if (z == 1) {
        float s = 0.125f * Wo[cg >> 6];             // fold Wo/sqrt(64) into K columns
#pragma unroll
        for (int i = 0; i < 4; i++)
          Ks[(size_t)(rg + i) * HD + cg] = f2bf(fmaxf(acc[fm][fn][i] + b, 0.0f) * s);
      } else {
#pragma unroll
        for (int i = 0; i < 4; i++)
          Ql[(size_t)(rg + i) * HD + cg] = f2bf(fmaxf(acc[fm][fn][i] + b, 0.0f));
      }
    }
}

// ------------- logits = Ql @ Ks^T : [2048,2048] f32, BN=128, 256 blocks ------------
__global__ __launch_bounds__(512)
void gemm_logits(const unsigned short* __restrict__ Ql, const unsigned short* __restrict__ Ks,
                 float* __restrict__ C) {
  __shared__ __align__(16) unsigned short lds[4 * 16384];  // 128 KB
  const int bid = blockIdx.x;
  const int x = bid & 7, j = bid >> 3;     // 32 per XCD
  const int bm = (x & 3) * 4 + (j >> 3);   // [0,16)
  const int bn = (x >> 2) * 8 + (j & 7);   // [0,16)

  f32x4 acc[4][2];
  mfma_pipeline<128, 16>(Ql + (size_t)bm * 128 * HD, Ks + (size_t)bn * 128 * HD, HD, HD, lds, acc);

  const int tid = threadIdx.x;
  const int lane = tid & 63, wave = tid >> 6;
  const int wr = wave >> 2, wc = wave & 3;
  const int l15 = lane & 15, hi = lane >> 4;
  const int row0 = bm * 128 + wr * 64;
  const int col0 = bn * 128 + wc * 32;
#pragma unroll
  for (int fm = 0; fm < 4; fm++)
#pragma unroll
    for (int fn = 0; fn < 2; fn++) {
      int cg = col0 + fn * 16 + l15;
      int rg = row0 + fm * 16 + hi * 4;
#pragma unroll
      for (int i = 0; i < 4; i++)
        C[(size_t)(rg + i) * TK + cg] = acc[fm][fn][i];
    }
}

// ------------- PV GEMM (full K=2048, 128 blocks) + attn.T transpose (1024 blocks) --
__global__ __launch_bounds__(512)
void pv_and_transpose(const unsigned short* __restrict__ attnb, const unsigned short* __restrict__ VT,
                      float* __restrict__ outp, float* __restrict__ attnT) {
  __shared__ __align__(16) unsigned short lds[4 * 16384];  // 128 KB
  const int bid = blockIdx.x;
  const int tid = threadIdx.x;
  if (bid < 128) {
    const int x = bid & 7, j = bid >> 3;    // 16 per XCD
    const int bm = (x & 3) * 4 + (j >> 2);  // [0,16)
    const int bn = (x >> 2) * 4 + (j & 3);  // [0,8)
    f32x4 acc[4][2];
    mfma_pipeline<128, 32>(attnb + (size_t)bm * 128 * TK, VT + (size_t)bn * 128 * TK,
                           TK, TK, lds, acc);
    const int lane = tid & 63, wave = tid >> 6;
    const int wr = wave >> 2, wc = wave & 3;
    const int l15 = lane & 15, hi = lane >> 4;
    const int row0 = bm * 128 + wr * 64;
    const int col0 = bn * 128 + wc * 32;
#pragma unroll
    for (int fm = 0; fm < 4; fm++)
#pragma unroll
      for (int fn = 0; fn < 2; fn++) {
        int cg = col0 + fn * 16 + l15;
        int rg = row0 + fm * 16 + hi * 4;
#pragma unroll
        for (int i = 0; i < 4; i++)
          outp[(size_t)(rg + i) * HD + cg] = acc[fm][fn][i];
      }
  } else {
    // transpose: bf16 attn [TQ][TK] tile (64x64) -> f32 attn.T [TK][TQ]
    unsigned short (*tile)[68] = reinterpret_cast<unsigned short (*)[68]>(lds);
    const int q0 = bid - 128;
    const int tr = (q0 >> 5) * 64;   // source row block
    const int tc = (q0 & 31) * 64;   // source col block
#pragma unroll
    for (int i = 0; i < 2; i++) {
      int q = i * 512 + tid;
      int r = q >> 4;
      int c4 = (q & 15) * 4;
      u16x4 v = *(const u16x4*)(attnb + (size_t)(tr + r) * TK + tc + c4);
      *(u16x4*)(&tile[r][c4]) = v;
    }
    __syncthreads();
#pragma unroll
    for (int i = 0; i < 2; i++) {
      int q = i * 512 + tid;
      int c = q >> 4;
      int r4 = (q & 15) * 4;
      f32x4 o;
#pragma unroll
      for (int jx = 0; jx < 4; jx++) o[jx] = bf2f(tile[r4 + jx][c]);
      *(f32x4*)(attnT + (size_t)(tc + c) * TQ + tr + r4) = o;
    }
  }
}

// ------------- row softmax over 2048 logits -> bf16 attn ---------------------------
__global__ __launch_bounds__(256)
void softmax_k(const float* __restrict__ logits, unsigned short* __restrict__ attnb) {
  const int row = blockIdx.x;
  const int tid = threadIdx.x;
  const int lane = tid & 63;
  const int wave = tid >> 6;
  const float* lr = logits + (size_t)row * TK;

  f32x4 v0 = *(const f32x4*)(lr + tid * 8);
  f32x4 v1 = *(const f32x4*)(lr + tid * 8 + 4);
  float x[8];
#pragma unroll
  for (int j = 0; j < 4; j++) { x[j] = v0[j]; x[4 + j] = v1[j]; }

  float m = x[0];
#pragma unroll
  for (int j = 1; j < 8; j++) m = fmaxf(m, x[j]);
  for (int o = 32; o > 0; o >>= 1) m = fmaxf(m, __shfl_xor(m, o));
  __shared__ float redm[4], reds[4];
  if (lane == 0) redm[wave] = m;
  __syncthreads();
  m = fmaxf(fmaxf(redm[0], redm[1]), fmaxf(redm[2], redm[3]));

  const float L2E = 1.44269504088896341f;
  float e[8];
  float s = 0.0f;
#pragma unroll
  for (int j = 0; j < 8; j++) { e[j] = exp2f((x[j] - m) * L2E); s += e[j]; }
  for (int o = 32; o > 0; o >>= 1) s += __shfl_xor(s, o);
  if (lane == 0) reds[wave] = s;
  __syncthreads();
  s = reds[0] + reds[1] + reds[2] + reds[3];
  float inv = 1.0f / s;

  unsigned short* ar = attnb + (size_t)row * TK;
  u16x4 o0, o1;
#pragma unroll
  for (int j = 0; j < 4; j++) { o0[j] = f2bf(e[j] * inv); o1[j] = f2bf(e[4 + j] * inv); }
  *(u16x4*)(ar + tid * 8) = o0;
  *(u16x4*)(ar + tid * 8 + 4) = o1;
}

// ------------- all six f32 -> bf16 converts in one launch --------------------------
__global__ __launch_bounds__(256)
void cvt6(const float* __restrict__ Q, const float* __restrict__ K, const float* __restrict__ V,
          const float* __restrict__ Wq, const float* __restrict__ Wk, const float* __restrict__ Wv,
          unsigned short* __restrict__ Qb, unsigned short* __restrict__ Kb,
          unsigned short* __restrict__ Vb, unsigned short* __restrict__ Wqb,
          unsigned short* __restrict__ Wkb, unsigned short* __restrict__ Wvb) {
  const int y = blockIdx.y;
  const float* s;
  unsigned short* d;
  int n4;
  switch (y) {
    case 0: s = Q;  d = Qb;  n4 = TQ * HD / 4; break;
    case 1: s = K;  d = Kb;  n4 = TK * HD / 4; break;
    case 2: s = V;  d = Vb;  n4 = TK * HD / 4; break;
    case 3: s = Wq; d = Wqb; n4 = HD * HD / 4; break;
    case 4: s = Wk; d = Wkb; n4 = HD * HD / 4; break;
    default: s = Wv; d = Wvb; n4 = HD * HD / 4; break;
  }
  int i = blockIdx.x * 256 + threadIdx.x;
  if (i < n4) {
    f32x4 v = *(const f32x4*)(s + i * 4);
    u16x4 o;
#pragma unroll
    for (int j = 0; j < 4; j++) o[j] = f2bf(v[j]);
    *(u16x4*)(d + i * 4) = o;
  }
}

extern "C" void kernel_launch(void* const* d_in, const int* in_sizes, int n_in,
                              void* d_out, int out_size, void* d_ws, size_t ws_size,
                              hipStream_t stream) {
  const float* Q  = (const float*)d_in[0];
  const float* K  = (const float*)d_in[1];
  const float* V  = (const float*)d_in[2];
  const float* Wq = (const float*)d_in[3];
  const float* bq = (const float*)d_in[4];
  const float* Wk = (const float*)d_in[5];
  const float* bk = (const float*)d_in[6];
  const float* Wv = (const float*)d_in[7];
  const float* bv = (const float*)d_in[8];
  const float* Wo = (const float*)d_in[9];
  // bo unused: softmax shift-invariant.

  uint8_t* w = (uint8_t*)d_ws;
  unsigned short* Qb  = (unsigned short*)(w + 0);            // 4 MB
  unsigned short* Kb  = (unsigned short*)(w + 4194304);      // 4 MB
  unsigned short* Vb  = (unsigned short*)(w + 8388608);      // 4 MB
  unsigned short* Wqb = (unsigned short*)(w + 12582912);     // 2 MB
  unsigned short* Wkb = (unsigned short*)(w + 14680064);     // 2 MB
  unsigned short* Wvb = (unsigned short*)(w + 16777216);     // 2 MB
  unsigned short* Ql  = (unsigned short*)(w + 18874368);     // 4 MB
  unsigned short* Ks  = (unsigned short*)(w + 23068672);     // 4 MB
  unsigned short* VT  = (unsigned short*)(w + 27262976);     // 4 MB
  float*          logits = (float*)(w + 31457280);           // 16 MB
  unsigned short* attnb  = (unsigned short*)(w + 48234496);  // 8 MB

  float* outp  = (float*)d_out;              // [2048][1024]
  float* attnT = outp + (size_t)TQ * HD;     // [2048][2048]

  cvt6<<<dim3(2048, 6), dim3(256), 0, stream>>>(Q, K, V, Wq, Wk, Wv, Qb, Kb, Vb, Wqb, Wkb, Wvb);

  // projections: M=2048, N=1024, K=1024, z in {Q,K,V}; 768 blocks = 3 full rounds
  gemm_proj<<<dim3(768), dim3(512), 0, stream>>>(Qb, Kb, Vb, Wqb, Wkb, Wvb,
                                                 bq, bk, bv, Wo, Ql, Ks, VT);

  // logits: M=2048, N=2048, K=1024; 256 blocks
  gemm_logits<<<dim3(256), dim3(512), 0, stream>>>(Ql, Ks, logits);

  softmax_k<<<dim3(TQ), dim3(256), 0, stream>>>(logits, attnb);

  // PV (M=2048,N=1024,K=2048; 128 blocks) + transpose (1024 blocks), one launch
  pv_and_transpose<<<dim3(1152), dim3(512), 0, stream>>>(attnb, VT, outp, attnT);
}

// Round 4
// 73.787 us; speedup vs baseline: 1.6587x; 1.1260x over previous
//
#include <hip/hip_runtime.h>
#include <stdint.h>

// Multihead_Attention on MI355X (gfx950).
// proj reads f32 Q/K/V/W directly (reg-staged cvt->LDS, no separate convert pass),
// relu + Wo/8 folded into K cols, V stored transposed -> logits GEMM -> softmax
// -> [PV GEMM + attn.T transpose in one launch].
// GEMM core: bf16 MFMA 16x16x32, BM=128, BK=64, 512 thr, XOR chunk swizzle,
// counted s_waitcnt vmcnt(N) pipelines (T3+T4), 1 barrier/iter, setprio (T5),
// XCD rectangle swizzle.

#define TQ 2048
#define TK 2048
#define HD 1024

#define DEVI __device__ __forceinline__

typedef __attribute__((ext_vector_type(8))) short bf16x8;
typedef __attribute__((ext_vector_type(4))) float f32x4;
typedef __attribute__((ext_vector_type(4))) unsigned short u16x4;
typedef unsigned short ushort_t;

DEVI unsigned short f2bf(float f) {
  uint32_t u = __builtin_bit_cast(uint32_t, f);
  u += 0x7FFFu + ((u >> 16) & 1u);
  return (unsigned short)(u >> 16);
}
DEVI float bf2f(unsigned short h) {
  uint32_t u = ((uint32_t)h) << 16;
  return __builtin_bit_cast(float, u);
}
DEVI void gload_lds16(const void* g, void* l) {
  __builtin_amdgcn_global_load_lds((const __attribute__((address_space(1))) void*)g,
                                   (__attribute__((address_space(3))) void*)l,
                                   16, 0, 0);
}
template<int N> DEVI void wait_vm() { asm volatile("s_waitcnt vmcnt(%0)" :: "n"(N) : "memory"); }
DEVI void wait_lgkm0() { asm volatile("s_waitcnt lgkmcnt(0)" ::: "memory"); }
#define SBAR() __builtin_amdgcn_s_barrier()

// ---- stage one K-step tile pair (A 128x64, B BNx64 bf16) into one LDS buffer.
// 512 threads. Linear LDS dest (gload_lds requirement), source col XOR-swizzled.
template<int BN>
DEVI void stageT(const unsigned short* __restrict__ A, const unsigned short* __restrict__ B,
                 int lda, int ldb, int k0, unsigned short* buf, int tid) {
#pragma unroll
  for (int i = 0; i < 2; i++) {              // A: 128 rows x 8 chunks = 1024 chunks
    int c = i * 512 + tid;
    int r = c >> 3;
    int cs = (c & 7) ^ (r & 7);
    gload_lds16(A + (size_t)r * lda + k0 + cs * 8, buf + c * 8);
  }
#pragma unroll
  for (int i = 0; i < BN / 64; i++) {        // B: BN rows x 8 chunks
    int c = i * 512 + tid;
    int r = c >> 3;
    int cs = (c & 7) ^ (r & 7);
    gload_lds16(B + (size_t)r * ldb + k0 + cs * 8, buf + 8192 + c * 8);
  }
}

// ---- one staged 64-K-step of MFMA. BN=128: wave 64x32 (acc[4][2]); BN=64: 32x32 (acc[2][2]).
template<int BN>
DEVI void computeT(const unsigned short* lA, const unsigned short* lB, f32x4 (*acc)[2],
                   int wr, int wc, int l15, int hi) {
  constexpr int FM = (BN == 128) ? 4 : 2;
  constexpr int WMR = (BN == 128) ? 64 : 32;
#pragma unroll
  for (int kk = 0; kk < 2; kk++) {
    bf16x8 af[4], bfr[2];
#pragma unroll
    for (int f = 0; f < FM; f++) {
      int ra = wr * WMR + f * 16 + l15;
      int ca = (kk * 4 + hi) ^ (ra & 7);
      af[f] = *(const bf16x8*)(lA + ra * 64 + ca * 8);
    }
#pragma unroll
    for (int f = 0; f < 2; f++) {
      int rb = wc * 32 + f * 16 + l15;
      int cb = (kk * 4 + hi) ^ (rb & 7);
      bfr[f] = *(const bf16x8*)(lB + rb * 64 + cb * 8);
    }
#pragma unroll
    for (int fm = 0; fm < FM; fm++)
#pragma unroll
      for (int fn = 0; fn < 2; fn++)
        acc[fm][fn] = __builtin_amdgcn_mfma_f32_16x16x32_bf16(af[fm], bfr[fn], acc[fm][fn], 0, 0, 0);
  }
}

// ---- gload_lds pipeline: 4 LDS buffers, depth-2 in flight, 1 barrier/iter.
// Ledger: reads of buf t guarded by [wait_vm -> SBAR] (each wave's own loads counted;
// barrier broadcasts). stage(t+3) targets buf (t+3)&3 != buf t&3 (current reads) and
// != t+1,t+2 (pending); WAR vs compute(t-1)'s reads of buf (t+3)&3=(t-1)&3 is safe
// because every wave's lgkm0 precedes SBAR(t), draining its ds_reads.
template<int BN, int NKT>
DEVI void mfma_pipeline(const unsigned short* __restrict__ A, const unsigned short* __restrict__ B,
                        int lda, int ldb, unsigned short* lds, f32x4 (*acc)[2]) {
  constexpr int FM = (BN == 128) ? 4 : 2;
  constexpr int LPS = 2 + BN / 64;           // loads per stage per thread (4 or 3)
  constexpr int BSTR = 8192 + BN * 64;       // buffer stride in shorts
  const int tid = threadIdx.x;
  const int lane = tid & 63, wave = tid >> 6;
  const int l15 = lane & 15, hi = lane >> 4;
  const int wr = (BN == 128) ? (wave >> 2) : (wave >> 1);
  const int wc = (BN == 128) ? (wave & 3) : (wave & 1);

#pragma unroll
  for (int i = 0; i < FM; i++)
#pragma unroll
    for (int j = 0; j < 2; j++) acc[i][j] = (f32x4)(0.0f);

#pragma unroll
  for (int s = 0; s < 3; s++) stageT<BN>(A, B, lda, ldb, s * 64, lds + s * BSTR, tid);

#pragma unroll 1
  for (int t = 0; t < NKT; ++t) {
    if (t < NKT - 2) wait_vm<2 * LPS>();
    else if (t == NKT - 2) wait_vm<LPS>();
    else wait_vm<0>();
    SBAR();                                   // buf t ready on every wave
    unsigned short* buf = lds + (t & 3) * BSTR;
    __builtin_amdgcn_s_setprio(1);
    computeT<BN>(buf, buf + 8192, acc, wr, wc, l15, hi);
    __builtin_amdgcn_s_setprio(0);
    wait_lgkm0();                             // my ds_reads drained (WAR safety)
    if (t + 3 < NKT) stageT<BN>(A, B, lda, ldb, (t + 3) * 64, lds + ((t + 3) & 3) * BSTR, tid);
  }
}

// ================= reg-staged f32 projection pipeline ==============================
// A tile 128x64 (f32 source), B tile 64x64 (f32 source). Per thread per stage:
// 3 chunks (2 A + 1 B) of 8 f32 = 6 dwordx4 loads -> cvt -> 3 ds_write_b128 to
// swizzled LDS (global chunk col g lands at LDS col g^(r&7), matching computeT).
DEVI void cvtw(unsigned short* dst, const f32x4& lo, const f32x4& hi) {
  bf16x8 o;
#pragma unroll
  for (int j = 0; j < 4; j++) { o[j] = (short)f2bf(lo[j]); o[4 + j] = (short)f2bf(hi[j]); }
  *(bf16x8*)dst = o;
}

#define PROJ_LOAD(k0, a0l, a0h, a1l, a1h, bl, bh)                                   \
  {                                                                                 \
    int c0 = tid, r0 = c0 >> 3, g0 = c0 & 7;                                        \
    const float* p0 = Af + (size_t)r0 * HD + (k0) + g0 * 8;                         \
    a0l = *(const f32x4*)p0; a0h = *(const f32x4*)(p0 + 4);                         \
    int c1 = tid + 512, r1 = c1 >> 3, g1 = c1 & 7;                                  \
    const float* p1 = Af + (size_t)r1 * HD + (k0) + g1 * 8;                         \
    a1l = *(const f32x4*)p1; a1h = *(const f32x4*)(p1 + 4);                         \
    int rb = tid >> 3, gb = tid & 7;                                                \
    const float* pb = Bf + (size_t)rb * HD + (k0) + gb * 8;                         \
    bl = *(const f32x4*)pb; bh = *(const f32x4*)(pb + 4);                           \
  }

#define PROJ_WRITE(buf, a0l, a0h, a1l, a1h, bl, bh)                                 \
  {                                                                                 \
    int c0 = tid, r0 = c0 >> 3, g0 = c0 & 7;                                        \
    cvtw((buf) + r0 * 64 + ((g0 ^ (r0 & 7)) * 8), a0l, a0h);                        \
    int c1 = tid + 512, r1 = c1 >> 3, g1 = c1 & 7;                                  \
    cvtw((buf) + r1 * 64 + ((g1 ^ (r1 & 7)) * 8), a1l, a1h);                        \
    int rb = tid >> 3, gb = tid & 7;                                                \
    cvtw((buf) + 8192 + rb * 64 + ((gb ^ (rb & 7)) * 8), bl, bh);                   \
  }

// Ledger (1 barrier/iter, 2 LDS bufs, 2 reg sets): ds_write buf[t&1] at iter t is
// WAR-safe vs compute(t-2) reads because those reads drained at lgkm0(t-1) before
// SBAR(t-1), and every wave writing at t has passed SBAR(t-1). RAW: compute(t)
// follows SBAR(t), which follows all waves' ds_writes + lgkm0. vmcnt: at iter t's
// wait_vm<6>, outstanding = set(t) [6, maybe done] + set(t+1) [6] -> set(t) done.
DEVI void proj_pipeline(const float* __restrict__ Af, const float* __restrict__ Bf,
                        unsigned short* lds, f32x4 (*acc)[2]) {
  const int tid = threadIdx.x;
  const int lane = tid & 63, wave = tid >> 6;
  const int l15 = lane & 15, hi = lane >> 4;
  const int wr = wave >> 1, wc = wave & 1;

#pragma unroll
  for (int i = 0; i < 2; i++)
#pragma unroll
    for (int j = 0; j < 2; j++) acc[i][j] = (f32x4)(0.0f);

  unsigned short* buf0 = lds;
  unsigned short* buf1 = lds + 12288;

  f32x4 Aa0l, Aa0h, Aa1l, Aa1h, Abl, Abh;   // set A (even tiles)
  f32x4 Ba0l, Ba0h, Ba1l, Ba1h, Bbl, Bbh;   // set B (odd tiles)
  PROJ_LOAD(0, Aa0l, Aa0h, Aa1l, Aa1h, Abl, Abh);
  PROJ_LOAD(64, Ba0l, Ba0h, Ba1l, Ba1h, Bbl, Bbh);

#pragma unroll 1
  for (int t = 0; t < 16; t += 2) {
    // even iter t
    wait_vm<6>();                             // set A (tile t) landed
    PROJ_WRITE(buf0, Aa0l, Aa0h, Aa1l, Aa1h, Abl, Abh);
    if (t + 2 < 16) PROJ_LOAD((t + 2) * 64, Aa0l, Aa0h, Aa1l, Aa1h, Abl, Abh);
    wait_lgkm0();
    SBAR();
    __builtin_amdgcn_s_setprio(1);
    computeT<64>(buf0, buf0 + 8192, acc, wr, wc, l15, hi);
    __builtin_amdgcn_s_setprio(0);
    // odd iter t+1
    if (t == 14) wait_vm<0>(); else wait_vm<6>();
    PROJ_WRITE(buf1, Ba0l, Ba0h, Ba1l, Ba1h, Bbl, Bbh);
    if (t + 3 < 16) PROJ_LOAD((t + 3) * 64, Ba0l, Ba0h, Ba1l, Ba1h, Bbl, Bbh);
    wait_lgkm0();
    SBAR();
    __builtin_amdgcn_s_setprio(1);
    computeT<64>(buf1, buf1 + 8192, acc, wr, wc, l15, hi);
    __builtin_amdgcn_s_setprio(0);
  }
}

// ------------- batched projection: relu(X @ W^T + b) from f32 inputs ---------------
__global__ __launch_bounds__(512)
void gemm_proj(const float* __restrict__ Qf, const float* __restrict__ Kf,
               const float* __restrict__ Vf,
               const float* __restrict__ Wqf, const float* __restrict__ Wkf,
               const float* __restrict__ Wvf,
               const float* __restrict__ bq, const float* __restrict__ bk,
               const float* __restrict__ bv, const float* __restrict__ Wo,
               unsigned short* __restrict__ Ql, unsigned short* __restrict__ Ks,
               unsigned short* __restrict__ VT) {
  __shared__ __align__(16) unsigned short lds[2 * 12288];  // 48 KB
  const int bid = blockIdx.x;
  const int x = bid & 7, j = bid >> 3;     // XCD, index within (96 per XCD)
  const int z = j >> 5;                    // 32 tiles per z per XCD
  const int jj = j & 31;
  const int bm = (x & 3) * 4 + (jj >> 3);  // [0,16)
  const int bn = (x >> 2) * 8 + (jj & 7);  // [0,16)

  const float* Af = ((z == 0) ? Qf : (z == 1) ? Kf : Vf) + (size_t)bm * 128 * HD;
  const float* Bf = ((z == 0) ? Wqf : (z == 1) ? Wkf : Wvf) + (size_t)bn * 64 * HD;
  const float* bias = (z == 0) ? bq : (z == 1) ? bk : bv;

  f32x4 acc[2][2];
  proj_pipeline(Af, Bf, lds, acc);

  const int tid = threadIdx.x;
  const int lane = tid & 63, wave = tid >> 6;
  const int wr = wave >> 1, wc = wave & 1;
  const int l15 = lane & 15, hi = lane >> 4;
  const int row0 = bm * 128 + wr * 32;
  const int col0 = bn * 64 + wc * 32;

#pragma unroll
  for (int fm = 0; fm < 2; fm++)
#pragma unroll
    for (int fn = 0; fn < 2; fn++) {
      int cg = col0 + fn * 16 + l15;
      int rg = row0 + fm * 16 + hi * 4;
      float b = bias[cg];
      if (z == 2) {
        u16x4 o;
#pragma unroll
        for (int i = 0; i < 4; i++) o[i] = f2bf(fmaxf(acc[fm][fn][i] + b, 0.0f));
        *(u16x4*)(VT + (size_t)cg * TK + rg) = o;   // transposed store for PV B operand
      } else if (z == 1) {
        float s = 0.125f * Wo[cg >> 6];             // fold Wo/sqrt(64) into K columns
#pragma unroll
        for (int i = 0; i < 4; i++)
          Ks[(size_t)(rg + i) * HD + cg] = f2bf(fmaxf(acc[fm][fn][i] + b, 0.0f) * s);
      } else {
#pragma unroll
        for (int i = 0; i < 4; i++)
          Ql[(size_t)(rg + i) * HD + cg] = f2bf(fmaxf(acc[fm][fn][i] + b, 0.0f));
      }
    }
}

// ------------- logits = Ql @ Ks^T : [2048,2048] f32, BN=128, 256 blocks ------------
__global__ __launch_bounds__(512)
void gemm_logits(const unsigned short* __restrict__ Ql, const unsigned short* __restrict__ Ks,
                 float* __restrict__ C) {
  __shared__ __align__(16) unsigned short lds[4 * 16384];  // 128 KB
  const int bid = blockIdx.x;
  const int x = bid & 7, j = bid >> 3;     // 32 per XCD
  const int bm = (x & 3) * 4 + (j >> 3);   // [0,16)
  const int bn = (x >> 2) * 8 + (j & 7);   // [0,16)

  f32x4 acc[4][2];
  mfma_pipeline<128, 16>(Ql + (size_t)bm * 128 * HD, Ks + (size_t)bn * 128 * HD, HD, HD, lds, acc);

  const int tid = threadIdx.x;
  const int lane = tid & 63, wave = tid >> 6;
  const int wr = wave >> 2, wc = wave & 3;
  const int l15 = lane & 15, hi = lane >> 4;
  const int row0 = bm * 128 + wr * 64;
  const int col0 = bn * 128 + wc * 32;
#pragma unroll
  for (int fm = 0; fm < 4; fm++)
#pragma unroll
    for (int fn = 0; fn < 2; fn++) {
      int cg = col0 + fn * 16 + l15;
      int rg = row0 + fm * 16 + hi * 4;
#pragma unroll
      for (int i = 0; i < 4; i++)
        C[(size_t)(rg + i) * TK + cg] = acc[fm][fn][i];
    }
}

// ------------- PV GEMM (full K=2048, 128 blocks) + attn.T transpose (1024 blocks) --
__global__ __launch_bounds__(512)
void pv_and_transpose(const unsigned short* __restrict__ attnb, const unsigned short* __restrict__ VT,
                      float* __restrict__ outp, float* __restrict__ attnT) {
  __shared__ __align__(16) unsigned short lds[4 * 16384];  // 128 KB
  const int bid = blockIdx.x;
  const int tid = threadIdx.x;
  if (bid < 128) {
    const int x = bid & 7, j = bid >> 3;    // 16 per XCD
    const int bm = (x & 3) * 4 + (j >> 2);  // [0,16)
    const int bn = (x >> 2) * 4 + (j & 3);  // [0,8)
    f32x4 acc[4][2];
    mfma_pipeline<128, 32>(attnb + (size_t)bm * 128 * TK, VT + (size_t)bn * 128 * TK,
                           TK, TK, lds, acc);
    const int lane = tid & 63, wave = tid >> 6;
    const int wr = wave >> 2, wc = wave & 3;
    const int l15 = lane & 15, hi = lane >> 4;
    const int row0 = bm * 128 + wr * 64;
    const int col0 = bn * 128 + wc * 32;
#pragma unroll
    for (int fm = 0; fm < 4; fm++)
#pragma unroll
      for (int fn = 0; fn < 2; fn++) {
        int cg = col0 + fn * 16 + l15;
        int rg = row0 + fm * 16 + hi * 4;
#pragma unroll
        for (int i = 0; i < 4; i++)
          outp[(size_t)(rg + i) * HD + cg] = acc[fm][fn][i];
      }
  } else {
    // transpose: bf16 attn [TQ][TK] tile (64x64) -> f32 attn.T [TK][TQ]
    unsigned short (*tile)[68] = reinterpret_cast<unsigned short (*)[68]>(lds);
    const int q0 = bid - 128;
    const int tr = (q0 >> 5) * 64;   // source row block
    const int tc = (q0 & 31) * 64;   // source col block
#pragma unroll
    for (int i = 0; i < 2; i++) {
      int q = i * 512 + tid;
      int r = q >> 4;
      int c4 = (q & 15) * 4;
      u16x4 v = *(const u16x4*)(attnb + (size_t)(tr + r) * TK + tc + c4);
      *(u16x4*)(&tile[r][c4]) = v;
    }
    __syncthreads();
#pragma unroll
    for (int i = 0; i < 2; i++) {
      int q = i * 512 + tid;
      int c = q >> 4;
      int r4 = (q & 15) * 4;
      f32x4 o;
#pragma unroll
      for (int jx = 0; jx < 4; jx++) o[jx] = bf2f(tile[r4 + jx][c]);
      *(f32x4*)(attnT + (size_t)(tc + c) * TQ + tr + r4) = o;
    }
  }
}

// ------------- row softmax over 2048 logits -> bf16 attn ---------------------------
__global__ __launch_bounds__(256)
void softmax_k(const float* __restrict__ logits, unsigned short* __restrict__ attnb) {
  const int row = blockIdx.x;
  const int tid = threadIdx.x;
  const int lane = tid & 63;
  const int wave = tid >> 6;
  const float* lr = logits + (size_t)row * TK;

  f32x4 v0 = *(const f32x4*)(lr + tid * 8);
  f32x4 v1 = *(const f32x4*)(lr + tid * 8 + 4);
  float x[8];
#pragma unroll
  for (int j = 0; j < 4; j++) { x[j] = v0[j]; x[4 + j] = v1[j]; }

  float m = x[0];
#pragma unroll
  for (int j = 1; j < 8; j++) m = fmaxf(m, x[j]);
  for (int o = 32; o > 0; o >>= 1) m = fmaxf(m, __shfl_xor(m, o));
  __shared__ float redm[4], reds[4];
  if (lane == 0) redm[wave] = m;
  __syncthreads();
  m = fmaxf(fmaxf(redm[0], redm[1]), fmaxf(redm[2], redm[3]));

  const float L2E = 1.44269504088896341f;
  float e[8];
  float s = 0.0f;
#pragma unroll
  for (int j = 0; j < 8; j++) { e[j] = exp2f((x[j] - m) * L2E); s += e[j]; }
  for (int o = 32; o > 0; o >>= 1) s += __shfl_xor(s, o);
  if (lane == 0) reds[wave] = s;
  __syncthreads();
  s = reds[0] + reds[1] + reds[2] + reds[3];
  float inv = 1.0f / s;

  unsigned short* ar = attnb + (size_t)row * TK;
  u16x4 o0, o1;
#pragma unroll
  for (int j = 0; j < 4; j++) { o0[j] = f2bf(e[j] * inv); o1[j] = f2bf(e[4 + j] * inv); }
  *(u16x4*)(ar + tid * 8) = o0;
  *(u16x4*)(ar + tid * 8 + 4) = o1;
}

extern "C" void kernel_launch(void* const* d_in, const int* in_sizes, int n_in,
                              void* d_out, int out_size, void* d_ws, size_t ws_size,
                              hipStream_t stream) {
  const float* Q  = (const float*)d_in[0];
  const float* K  = (const float*)d_in[1];
  const float* V  = (const float*)d_in[2];
  const float* Wq = (const float*)d_in[3];
  const float* bq = (const float*)d_in[4];
  const float* Wk = (const float*)d_in[5];
  const float* bk = (const float*)d_in[6];
  const float* Wv = (const float*)d_in[7];
  const float* bv = (const float*)d_in[8];
  const float* Wo = (const float*)d_in[9];
  // bo unused: softmax shift-invariant.

  uint8_t* w = (uint8_t*)d_ws;
  unsigned short* Ql  = (unsigned short*)(w + 0);            // 4 MB
  unsigned short* Ks  = (unsigned short*)(w + 4194304);      // 4 MB
  unsigned short* VT  = (unsigned short*)(w + 8388608);      // 4 MB
  float*          logits = (float*)(w + 12582912);           // 16 MB
  unsigned short* attnb  = (unsigned short*)(w + 29360128);  // 8 MB
  // total 37,748,736 bytes

  float* outp  = (float*)d_out;              // [2048][1024]
  float* attnT = outp + (size_t)TQ * HD;     // [2048][2048]

  // projections from f32: M=2048, N=1024, K=1024, z in {Q,K,V}; 768 blocks
  gemm_proj<<<dim3(768), dim3(512), 0, stream>>>(Q, K, V, Wq, Wk, Wv,
                                                 bq, bk, bv, Wo, Ql, Ks, VT);

  // logits: M=2048, N=2048, K=1024; 256 blocks
  gemm_logits<<<dim3(256), dim3(512), 0, stream>>>(Ql, Ks, logits);

  softmax_k<<<dim3(TQ), dim3(256), 0, stream>>>(logits, attnb);

  // PV (M=2048,N=1024,K=2048; 128 blocks) + transpose (1024 blocks), one launch
  pv_and_transpose<<<dim3(1152), dim3(512), 0, stream>>>(attnb, VT, outp, attnT);
}